// Round 1
// baseline (522.700 us; speedup 1.0000x reference)
//
#include <hip/hip_runtime.h>
#include <stdint.h>

#define TDIM 2048
#define DMODEL 2048
#define NHEADS 16
#define DHEAD 128
#define NBATCH 2
#define NTOK (NBATCH * TDIM)   // 4096
#define NQKV (3 * DMODEL)      // 6144
#define BHTOT (NBATCH * NHEADS) // 32

typedef unsigned short u16;
typedef __attribute__((ext_vector_type(8))) short bf16x8;
typedef __attribute__((ext_vector_type(4))) float f32x4;
typedef __attribute__((ext_vector_type(4))) int i32x4;

__device__ __forceinline__ u16 f2bf(float f) {
  union { float f; uint32_t u; } v; v.f = f;
  uint32_t u = v.u + 0x7fffu + ((v.u >> 16) & 1u);
  return (u16)(u >> 16);
}
__device__ __forceinline__ float bf2f(u16 h) {
  union { uint32_t u; float f; } v; v.u = ((uint32_t)h) << 16;
  return v.f;
}

#define GLOAD16(g, l)                                                        \
  __builtin_amdgcn_global_load_lds(                                          \
      (const __attribute__((address_space(1))) void*)(g),                    \
      (__attribute__((address_space(3))) void*)(l), 16, 0, 0)

// ---------------- RoPE cos/sin table: ct/st[t][m], m in [0,64) ------------
__global__ void rope_table_kernel(float* __restrict__ ct, float* __restrict__ st) {
  int idx = blockIdx.x * 256 + threadIdx.x;   // TDIM*64 total
  int t = idx >> 6, m = idx & 63;
  // inv_freq[m] = 10000^(-m/64)
  float inv = expf(-(float)m * (9.210340371976184f / 64.0f));
  float ang = (float)t * inv;
  ct[idx] = cosf(ang);
  st[idx] = sinf(ang);
}

// ---------------- fp32 -> bf16 elementwise convert (float4) ---------------
__global__ void convert_kernel(const float* __restrict__ in, u16* __restrict__ out) {
  int i = blockIdx.x * 256 + threadIdx.x;
  float4 v = ((const float4*)in)[i];
  ushort4 o;
  o.x = f2bf(v.x); o.y = f2bf(v.y); o.z = f2bf(v.z); o.w = f2bf(v.w);
  ((ushort4*)out)[i] = o;
}

// ------------- fp32 (K,N) row-major -> bf16 (N,K) transposed ---------------
__global__ __launch_bounds__(256) void transpose_convert_kernel(
    const float* __restrict__ in, u16* __restrict__ out, int K, int N) {
  __shared__ u16 tile[32][33];
  int n0 = blockIdx.x * 32, k0 = blockIdx.y * 32;
  int tx = threadIdx.x, ty = threadIdx.y;
  #pragma unroll
  for (int q = 0; q < 4; q++) {
    int k = ty + q * 8;
    tile[k][tx] = f2bf(in[(size_t)(k0 + k) * N + n0 + tx]);
  }
  __syncthreads();
  #pragma unroll
  for (int q = 0; q < 4; q++) {
    int n = ty + q * 8;
    out[(size_t)(n0 + n) * K + k0 + tx] = tile[tx][n];
  }
}

// ---------------- bf16 transpose [BH][T][D] -> [BH][D][T] ------------------
__global__ __launch_bounds__(256) void vtrans_kernel(
    const u16* __restrict__ Vtmp, u16* __restrict__ Vt) {
  __shared__ u16 tile[32][33];
  int bh = blockIdx.z;
  int t0 = blockIdx.x * 32, d0 = blockIdx.y * 32;
  int tx = threadIdx.x, ty = threadIdx.y;
  const u16* src = Vtmp + (size_t)bh * TDIM * DHEAD;
  u16* dst = Vt + (size_t)bh * DHEAD * TDIM;
  #pragma unroll
  for (int q = 0; q < 4; q++) {
    int t = ty + q * 8;
    tile[t][tx] = src[(size_t)(t0 + t) * DHEAD + d0 + tx];
  }
  __syncthreads();
  #pragma unroll
  for (int q = 0; q < 4; q++) {
    int d = ty + q * 8;
    dst[(size_t)(d0 + d) * TDIM + t0 + tx] = tile[tx][d];
  }
}

// ---------------- in-place RoPE on [BH][T][128] bf16 ----------------------
__global__ void rope_kernel(u16* __restrict__ X, const float* __restrict__ ct,
                            const float* __restrict__ st, float scale) {
  int idx = blockIdx.x * 256 + threadIdx.x;   // BH*T*64 pairs
  int i = idx & 63;
  int t = (idx >> 6) & (TDIM - 1);
  size_t base = (size_t)idx * 2;
  float x0 = bf2f(X[base]), x1 = bf2f(X[base + 1]);
  int j0 = (2 * i) & 63, j1 = (2 * i + 1) & 63;
  const float* ctt = ct + (size_t)t * 64;
  const float* stt = st + (size_t)t * 64;
  float c0 = ctt[j0], s0 = stt[j0], c1 = ctt[j1], s1 = stt[j1];
  X[base]     = f2bf((x0 * c0 - x1 * s0) * scale);
  X[base + 1] = f2bf((x1 * c1 + x0 * s1) * scale);
}

// ---------------- GEMM: A (M,K) bf16 @ Bt (N,K) bf16 ----------------------
// MODE 0: C = A@B + bias -> scatter bf16 into Q/K/V [b][h][t][d]
// MODE 1: C = A@B + bias -> fp32 row-major out
template <int MODE>
__global__ __launch_bounds__(256) void gemm_bt_kernel(
    const u16* __restrict__ A, const u16* __restrict__ Bt,
    const float* __restrict__ bias,
    u16* __restrict__ q_out, u16* __restrict__ k_out, u16* __restrict__ v_out,
    float* __restrict__ f_out, int K) {
  __shared__ u16 As[128 * 32];
  __shared__ u16 Bs[128 * 32];
  const int tid = threadIdx.x;
  const int lane = tid & 63;
  const int w = tid >> 6, wr = w >> 1, wc = w & 1;
  const int g = lane >> 4, c = lane & 15;
  const int m0 = blockIdx.x * 128, n0 = blockIdx.y * 128;
  const f32x4 zero = {0.f, 0.f, 0.f, 0.f};
  f32x4 acc[4][4];
  #pragma unroll
  for (int m = 0; m < 4; m++)
    #pragma unroll
    for (int n = 0; n < 4; n++) acc[m][n] = zero;
  const size_t rowb = (size_t)K * 2;

  for (int k0 = 0; k0 < K; k0 += 32) {
    #pragma unroll
    for (int i = 0; i < 2; i++) {
      int o = i * 4096 + tid * 16;
      int ar = o >> 6, ak = o & 63;
      GLOAD16((const char*)A + (size_t)(m0 + ar) * rowb + (size_t)k0 * 2 + ak,
              (char*)As + o);
      GLOAD16((const char*)Bt + (size_t)(n0 + ar) * rowb + (size_t)k0 * 2 + ak,
              (char*)Bs + o);
    }
    __syncthreads();
    bf16x8 afr[4], bfr[4];
    #pragma unroll
    for (int m = 0; m < 4; m++)
      afr[m] = *(const bf16x8*)(As + (wr * 64 + m * 16 + c) * 32 + g * 8);
    #pragma unroll
    for (int n = 0; n < 4; n++)
      bfr[n] = *(const bf16x8*)(Bs + (wc * 64 + n * 16 + c) * 32 + g * 8);
    #pragma unroll
    for (int m = 0; m < 4; m++)
      #pragma unroll
      for (int n = 0; n < 4; n++)
        acc[m][n] = __builtin_amdgcn_mfma_f32_16x16x32_bf16(afr[m], bfr[n],
                                                            acc[m][n], 0, 0, 0);
    __syncthreads();
  }

  // epilogue: D row=(lane>>4)*4+r, col=lane&15 per 16x16 frag
  #pragma unroll
  for (int m = 0; m < 4; m++) {
    #pragma unroll
    for (int n = 0; n < 4; n++) {
      int gcol = n0 + wc * 64 + n * 16 + c;
      float bv = bias[gcol];
      #pragma unroll
      for (int r = 0; r < 4; r++) {
        int grow = m0 + wr * 64 + m * 16 + g * 4 + r;
        float val = acc[m][n][r] + bv;
        if (MODE == 0) {
          int s = gcol >> 11;          // 0:q 1:k 2:v (uniform per block)
          int rem = gcol & 2047;
          int h = rem >> 7, d = rem & 127;
          int b = grow >> 11, t = grow & (TDIM - 1);
          size_t off = (((size_t)(b * NHEADS + h)) * TDIM + t) * DHEAD + d;
          u16 hv = f2bf(val);
          if (s == 0) q_out[off] = hv;
          else if (s == 1) k_out[off] = hv;
          else v_out[off] = hv;
        } else {
          f_out[(size_t)grow * DMODEL + gcol] = val;
        }
      }
    }
  }
}

// ---------------- Flash attention (causal), 4 waves x 16 q-rows -----------
// Q,K: [BH][T][128] bf16 (Q pre-scaled by 1/sqrt(128)); Vt: [BH][128][T]
// Yattn: [B][T][H*128] bf16
__global__ __launch_bounds__(256) void attn_kernel(
    const u16* __restrict__ Q, const u16* __restrict__ K,
    const u16* __restrict__ Vt, u16* __restrict__ Yattn) {
  __shared__ u16 Ks[64 * 128];   // [kv][d], swizzled
  __shared__ u16 Vs[128 * 64];   // [d][kv], swizzled
  __shared__ u16 Ps[4][16 * 64]; // per-wave P tile, swizzled
  const int tid = threadIdx.x, lane = tid & 63, w = tid >> 6;
  const int g = lane >> 4, c = lane & 15;
  const int bh = blockIdx.y, b = bh >> 4, h = bh & 15;
  const int qt = blockIdx.x;
  const int qb = qt * 64 + w * 16;
  const u16* Qp = Q + (size_t)bh * TDIM * DHEAD;
  const u16* Kp = K + (size_t)bh * TDIM * DHEAD;
  const u16* Vp = Vt + (size_t)bh * DHEAD * TDIM;

  bf16x8 qf[4];
  #pragma unroll
  for (int kc = 0; kc < 4; kc++)
    qf[kc] = *(const bf16x8*)(Qp + (size_t)(qb + c) * DHEAD + kc * 32 + g * 8);

  const f32x4 zero = {0.f, 0.f, 0.f, 0.f};
  f32x4 po[8];
  #pragma unroll
  for (int df = 0; df < 8; df++) po[df] = zero;
  float mrun[4], lrun[4];
  #pragma unroll
  for (int r = 0; r < 4; r++) { mrun[r] = -1e30f; lrun[r] = 0.f; }

  const int nt = qt + 1;
  for (int tkv = 0; tkv < nt; tkv++) {
    int kv0 = tkv * 64;
    // stage K tile [64][128] and Vt tile [128][64], XOR-swizzled
    #pragma unroll
    for (int p = 0; p < 4; p++) {
      int o = p * 4096 + tid * 16;
      int kr = o >> 8, kcb = o & 255;
      i32x4 kv = *(const i32x4*)((const char*)Kp + (size_t)(kv0 + kr) * 256 + kcb);
      *(i32x4*)((char*)Ks + kr * 256 + (kcb ^ ((kr & 7) << 4))) = kv;
      int vr = o >> 7, vcb = o & 127;
      i32x4 vv = *(const i32x4*)((const char*)Vp + (size_t)vr * (TDIM * 2) +
                                 (size_t)kv0 * 2 + vcb);
      *(i32x4*)((char*)Vs + vr * 128 + (vcb ^ ((vr & 7) << 4))) = vv;
    }
    __syncthreads();

    // S = Q @ K^T  (16 x 64 per wave)
    f32x4 sa[4];
    #pragma unroll
    for (int n = 0; n < 4; n++) sa[n] = zero;
    #pragma unroll
    for (int n = 0; n < 4; n++) {
      int krow = n * 16 + c;
      #pragma unroll
      for (int kc = 0; kc < 4; kc++) {
        int kb = (kc * 32 + g * 8) * 2;
        bf16x8 kf = *(const bf16x8*)((const char*)Ks + krow * 256 +
                                     (kb ^ ((krow & 7) << 4)));
        sa[n] = __builtin_amdgcn_mfma_f32_16x16x32_bf16(qf[kc], kf, sa[n], 0, 0, 0);
      }
    }

    // causal mask + online softmax (rows g*4+r, cols n*16+c)
    float pvals[4][4];
    #pragma unroll
    for (int r = 0; r < 4; r++) {
      int qrow = qb + g * 4 + r;
      float sv[4];
      float vmax = -1e30f;
      #pragma unroll
      for (int n = 0; n < 4; n++) {
        int col = kv0 + n * 16 + c;
        float s = sa[n][r];
        if (col > qrow) s = -1e30f;
        sv[n] = s;
        vmax = fmaxf(vmax, s);
      }
      #pragma unroll
      for (int d = 1; d < 16; d <<= 1) vmax = fmaxf(vmax, __shfl_xor(vmax, d, 64));
      float mnew = fmaxf(mrun[r], vmax);
      float scale = __expf(mrun[r] - mnew);
      float rs = 0.f;
      #pragma unroll
      for (int n = 0; n < 4; n++) {
        float p = __expf(sv[n] - mnew);
        pvals[r][n] = p;
        rs += p;
      }
      #pragma unroll
      for (int d = 1; d < 16; d <<= 1) rs += __shfl_xor(rs, d, 64);
      lrun[r] = lrun[r] * scale + rs;
      mrun[r] = mnew;
      #pragma unroll
      for (int df = 0; df < 8; df++) po[df][r] *= scale;
    }

    // P -> LDS (per-wave region, swizzled), then PV
    char* Pw = (char*)&Ps[w][0];
    #pragma unroll
    for (int r = 0; r < 4; r++) {
      int ri = g * 4 + r;
      #pragma unroll
      for (int n = 0; n < 4; n++) {
        int colb = (n * 16 + c) * 2;
        *(u16*)(Pw + ri * 128 + (colb ^ ((ri & 7) << 4))) = f2bf(pvals[r][n]);
      }
    }
    bf16x8 pa[2];
    #pragma unroll
    for (int kc2 = 0; kc2 < 2; kc2++) {
      int pb = (kc2 * 32 + g * 8) * 2;
      pa[kc2] = *(const bf16x8*)(Pw + c * 128 + (pb ^ ((c & 7) << 4)));
    }
    #pragma unroll
    for (int df = 0; df < 8; df++) {
      #pragma unroll
      for (int kc2 = 0; kc2 < 2; kc2++) {
        int vrow = df * 16 + c;
        int vb = (kc2 * 32 + g * 8) * 2;
        bf16x8 vf = *(const bf16x8*)((const char*)Vs + vrow * 128 +
                                     (vb ^ ((vrow & 7) << 4)));
        po[df] = __builtin_amdgcn_mfma_f32_16x16x32_bf16(pa[kc2], vf, po[df], 0, 0, 0);
      }
    }
    __syncthreads();
  }

  float inv[4];
  #pragma unroll
  for (int r = 0; r < 4; r++) inv[r] = 1.0f / lrun[r];
  #pragma unroll
  for (int df = 0; df < 8; df++) {
    #pragma unroll
    for (int r = 0; r < 4; r++) {
      int t = qb + g * 4 + r;
      int col = h * DHEAD + df * 16 + c;
      Yattn[((size_t)b * TDIM + t) * DMODEL + col] = f2bf(po[df][r] * inv[r]);
    }
  }
}

extern "C" void kernel_launch(void* const* d_in, const int* in_sizes, int n_in,
                              void* d_out, int out_size, void* d_ws, size_t ws_size,
                              hipStream_t stream) {
  const float* x    = (const float*)d_in[0];
  // d_in[1] = mask (exact causal triu; implemented analytically)
  const float* Wqkv = (const float*)d_in[2];
  const float* bqkv = (const float*)d_in[3];
  const float* Wo   = (const float*)d_in[4];
  const float* bo   = (const float*)d_in[5];
  float* out = (float*)d_out;

  char* ws = (char*)d_ws;
  size_t o = 0;
  u16* xb    = (u16*)(ws + o); o += (size_t)NTOK * DMODEL * 2;     // 16.8 MB
  u16* Wqkvt = (u16*)(ws + o); o += (size_t)NQKV * DMODEL * 2;     // 25.2 MB
  u16* Wot   = (u16*)(ws + o); o += (size_t)DMODEL * DMODEL * 2;   // 8.4 MB
  u16* Qb    = (u16*)(ws + o); o += (size_t)BHTOT * TDIM * DHEAD * 2;
  u16* Kb    = (u16*)(ws + o); o += (size_t)BHTOT * TDIM * DHEAD * 2;
  u16* Vtmp  = (u16*)(ws + o); o += (size_t)BHTOT * TDIM * DHEAD * 2;
  float* ct  = (float*)(ws + o); o += (size_t)TDIM * 64 * 4;
  float* st  = (float*)(ws + o); o += (size_t)TDIM * 64 * 4;
  u16* Vt    = xb;    // alias: xb dead after GEMM1
  u16* Yattn = Vtmp;  // alias: Vtmp dead after vtrans

  dim3 tb32x8(32, 8);

  rope_table_kernel<<<(TDIM * 64) / 256, 256, 0, stream>>>(ct, st);
  convert_kernel<<<(NTOK * DMODEL / 4) / 256, 256, 0, stream>>>(x, xb);
  transpose_convert_kernel<<<dim3(NQKV / 32, DMODEL / 32), tb32x8, 0, stream>>>(
      Wqkv, Wqkvt, DMODEL, NQKV);
  transpose_convert_kernel<<<dim3(DMODEL / 32, DMODEL / 32), tb32x8, 0, stream>>>(
      Wo, Wot, DMODEL, DMODEL);

  gemm_bt_kernel<0><<<dim3(NTOK / 128, NQKV / 128), 256, 0, stream>>>(
      xb, Wqkvt, bqkv, Qb, Kb, Vtmp, nullptr, DMODEL);

  rope_kernel<<<(BHTOT * TDIM * 64) / 256, 256, 0, stream>>>(
      Qb, ct, st, 0.08838834764831845f);  // 1/sqrt(128)
  rope_kernel<<<(BHTOT * TDIM * 64) / 256, 256, 0, stream>>>(Kb, ct, st, 1.0f);

  vtrans_kernel<<<dim3(TDIM / 32, DHEAD / 32, BHTOT), tb32x8, 0, stream>>>(Vtmp, Vt);

  attn_kernel<<<dim3(TDIM / 64, BHTOT), 256, 0, stream>>>(Qb, Kb, Vt, Yattn);

  gemm_bt_kernel<1><<<dim3(NTOK / 128, DMODEL / 128), 256, 0, stream>>>(
      Yattn, Wot, bo, nullptr, nullptr, nullptr, out, DMODEL);
}

// Round 2
// 366.990 us; speedup vs baseline: 1.4243x; 1.4243x over previous
//
#include <hip/hip_runtime.h>
#include <stdint.h>

#define TDIM 2048
#define DMODEL 2048
#define NHEADS 16
#define DHEAD 128
#define NBATCH 2
#define NTOK (NBATCH * TDIM)   // 4096
#define NQKV (3 * DMODEL)      // 6144
#define BHTOT (NBATCH * NHEADS) // 32

typedef unsigned short u16;
typedef __attribute__((ext_vector_type(8))) short bf16x8;
typedef __attribute__((ext_vector_type(4))) float f32x4;
typedef __attribute__((ext_vector_type(4))) int i32x4;

__device__ __forceinline__ u16 f2bf(float f) {
  union { float f; uint32_t u; } v; v.f = f;
  uint32_t u = v.u + 0x7fffu + ((v.u >> 16) & 1u);
  return (u16)(u >> 16);
}
__device__ __forceinline__ float bf2f(u16 h) {
  union { uint32_t u; float f; } v; v.u = ((uint32_t)h) << 16;
  return v.f;
}

#define GLOAD16(g, l)                                                        \
  __builtin_amdgcn_global_load_lds(                                          \
      (const __attribute__((address_space(1))) void*)(g),                    \
      (__attribute__((address_space(3))) void*)(l), 16, 0, 0)

// ---------------- RoPE cos/sin table: ct/st[t][m], m in [0,64) ------------
__global__ void rope_table_kernel(float* __restrict__ ct, float* __restrict__ st) {
  int idx = blockIdx.x * 256 + threadIdx.x;   // TDIM*64 total
  int t = idx >> 6, m = idx & 63;
  float inv = expf(-(float)m * (9.210340371976184f / 64.0f));
  float ang = (float)t * inv;
  ct[idx] = cosf(ang);
  st[idx] = sinf(ang);
}

// ---------------- fp32 -> bf16 elementwise convert (float4) ---------------
__global__ void convert_kernel(const float* __restrict__ in, u16* __restrict__ out) {
  int i = blockIdx.x * 256 + threadIdx.x;
  float4 v = ((const float4*)in)[i];
  ushort4 o;
  o.x = f2bf(v.x); o.y = f2bf(v.y); o.z = f2bf(v.z); o.w = f2bf(v.w);
  ((ushort4*)out)[i] = o;
}

// ------------- fp32 (K,N) row-major -> bf16 (N,K) transposed ---------------
__global__ __launch_bounds__(256) void transpose_convert_kernel(
    const float* __restrict__ in, u16* __restrict__ out, int K, int N) {
  __shared__ u16 tile[32][33];
  int n0 = blockIdx.x * 32, k0 = blockIdx.y * 32;
  int tx = threadIdx.x, ty = threadIdx.y;
  #pragma unroll
  for (int q = 0; q < 4; q++) {
    int k = ty + q * 8;
    tile[k][tx] = f2bf(in[(size_t)(k0 + k) * N + n0 + tx]);
  }
  __syncthreads();
  #pragma unroll
  for (int q = 0; q < 4; q++) {
    int n = ty + q * 8;
    out[(size_t)(n0 + n) * K + k0 + tx] = tile[tx][n];
  }
}

// ---------------- bf16 transpose [BH][T][D] -> [BH][D][T] ------------------
__global__ __launch_bounds__(256) void vtrans_kernel(
    const u16* __restrict__ Vtmp, u16* __restrict__ Vt) {
  __shared__ u16 tile[32][33];
  int bh = blockIdx.z;
  int t0 = blockIdx.x * 32, d0 = blockIdx.y * 32;
  int tx = threadIdx.x, ty = threadIdx.y;
  const u16* src = Vtmp + (size_t)bh * TDIM * DHEAD;
  u16* dst = Vt + (size_t)bh * DHEAD * TDIM;
  #pragma unroll
  for (int q = 0; q < 4; q++) {
    int t = ty + q * 8;
    tile[t][tx] = src[(size_t)(t0 + t) * DHEAD + d0 + tx];
  }
  __syncthreads();
  #pragma unroll
  for (int q = 0; q < 4; q++) {
    int d = ty + q * 8;
    dst[(size_t)(d0 + d) * TDIM + t0 + tx] = tile[tx][d];
  }
}

// ---------------- in-place RoPE on [BH][T][128] bf16 ----------------------
__global__ void rope_kernel(u16* __restrict__ X, const float* __restrict__ ct,
                            const float* __restrict__ st, float scale) {
  int idx = blockIdx.x * 256 + threadIdx.x;   // BH*T*64 pairs
  int i = idx & 63;
  int t = (idx >> 6) & (TDIM - 1);
  size_t base = (size_t)idx * 2;
  float x0 = bf2f(X[base]), x1 = bf2f(X[base + 1]);
  int j0 = (2 * i) & 63, j1 = (2 * i + 1) & 63;
  const float* ctt = ct + (size_t)t * 64;
  const float* stt = st + (size_t)t * 64;
  float c0 = ctt[j0], s0 = stt[j0], c1 = ctt[j1], s1 = stt[j1];
  X[base]     = f2bf((x0 * c0 - x1 * s0) * scale);
  X[base + 1] = f2bf((x1 * c1 + x0 * s1) * scale);
}

// ---------------- GEMM: A (M,K) bf16 @ Bt (N,K) bf16 ----------------------
template <int MODE>
__global__ __launch_bounds__(256) void gemm_bt_kernel(
    const u16* __restrict__ A, const u16* __restrict__ Bt,
    const float* __restrict__ bias,
    u16* __restrict__ q_out, u16* __restrict__ k_out, u16* __restrict__ v_out,
    float* __restrict__ f_out, int K) {
  __shared__ u16 As[128 * 32];
  __shared__ u16 Bs[128 * 32];
  const int tid = threadIdx.x;
  const int lane = tid & 63;
  const int w = tid >> 6, wr = w >> 1, wc = w & 1;
  const int g = lane >> 4, c = lane & 15;
  const int m0 = blockIdx.x * 128, n0 = blockIdx.y * 128;
  const f32x4 zero = {0.f, 0.f, 0.f, 0.f};
  f32x4 acc[4][4];
  #pragma unroll
  for (int m = 0; m < 4; m++)
    #pragma unroll
    for (int n = 0; n < 4; n++) acc[m][n] = zero;
  const size_t rowb = (size_t)K * 2;

  for (int k0 = 0; k0 < K; k0 += 32) {
    #pragma unroll
    for (int i = 0; i < 2; i++) {
      int o = i * 4096 + tid * 16;
      int ar = o >> 6, ak = o & 63;
      GLOAD16((const char*)A + (size_t)(m0 + ar) * rowb + (size_t)k0 * 2 + ak,
              (char*)As + o);
      GLOAD16((const char*)Bt + (size_t)(n0 + ar) * rowb + (size_t)k0 * 2 + ak,
              (char*)Bs + o);
    }
    __syncthreads();
    bf16x8 afr[4], bfr[4];
    #pragma unroll
    for (int m = 0; m < 4; m++)
      afr[m] = *(const bf16x8*)(As + (wr * 64 + m * 16 + c) * 32 + g * 8);
    #pragma unroll
    for (int n = 0; n < 4; n++)
      bfr[n] = *(const bf16x8*)(Bs + (wc * 64 + n * 16 + c) * 32 + g * 8);
    #pragma unroll
    for (int m = 0; m < 4; m++)
      #pragma unroll
      for (int n = 0; n < 4; n++)
        acc[m][n] = __builtin_amdgcn_mfma_f32_16x16x32_bf16(afr[m], bfr[n],
                                                            acc[m][n], 0, 0, 0);
    __syncthreads();
  }

  #pragma unroll
  for (int m = 0; m < 4; m++) {
    #pragma unroll
    for (int n = 0; n < 4; n++) {
      int gcol = n0 + wc * 64 + n * 16 + c;
      float bv = bias[gcol];
      #pragma unroll
      for (int r = 0; r < 4; r++) {
        int grow = m0 + wr * 64 + m * 16 + g * 4 + r;
        float val = acc[m][n][r] + bv;
        if (MODE == 0) {
          int s = gcol >> 11;          // 0:q 1:k 2:v (uniform per block)
          int rem = gcol & 2047;
          int h = rem >> 7, d = rem & 127;
          int b = grow >> 11, t = grow & (TDIM - 1);
          size_t off = (((size_t)(b * NHEADS + h)) * TDIM + t) * DHEAD + d;
          u16 hv = f2bf(val);
          if (s == 0) q_out[off] = hv;
          else if (s == 1) k_out[off] = hv;
          else v_out[off] = hv;
        } else {
          f_out[(size_t)grow * DMODEL + gcol] = val;
        }
      }
    }
  }
}

// ---------------- Flash attention (causal), 4 waves x 16 q-rows -----------
// Double-buffered K/V staging via global_load_lds (linear dest, pre-swizzled
// source); causal-paired q-tiles {i, 31-i} for uniform block work.
// Q,K: [BH][T][128] bf16 (Q pre-scaled); Vt: [BH][128][T]; Yattn: [B][T][HD]
__global__ __launch_bounds__(256) void attn_kernel(
    const u16* __restrict__ Q, const u16* __restrict__ K,
    const u16* __restrict__ Vt, u16* __restrict__ Yattn) {
  __shared__ u16 Ks[2][64 * 128];   // [kv][d], swizzle: chunk ^= row&7
  __shared__ u16 Vs[2][128 * 64];   // [d][kv], swizzle: chunk ^= row&7
  __shared__ u16 Ps[4][16 * 64];    // per-wave P tile, swizzled
  const int tid = threadIdx.x, lane = tid & 63, w = tid >> 6;
  const int g = lane >> 4, c = lane & 15;
  const int bh = blockIdx.y, b = bh >> 4, h = bh & 15;
  const u16* Qp = Q + (size_t)bh * TDIM * DHEAD;
  const u16* Kp = K + (size_t)bh * TDIM * DHEAD;
  const u16* Vp = Vt + (size_t)bh * DHEAD * TDIM;
  const f32x4 zero = {0.f, 0.f, 0.f, 0.f};

  for (int half = 0; half < 2; half++) {
    const int qt = half ? (31 - (int)blockIdx.x) : (int)blockIdx.x;
    const int qb = qt * 64 + w * 16;

    bf16x8 qf[4];
    #pragma unroll
    for (int kc = 0; kc < 4; kc++)
      qf[kc] = *(const bf16x8*)(Qp + (size_t)(qb + c) * DHEAD + kc * 32 + g * 8);

    f32x4 po[8];
    #pragma unroll
    for (int df = 0; df < 8; df++) po[df] = zero;
    float mrun[4], lrun[4];
    #pragma unroll
    for (int r = 0; r < 4; r++) { mrun[r] = -1e30f; lrun[r] = 0.f; }

    const int nt = qt + 1;

    // ---- prologue: stage tile 0 into buf 0 ----
    {
      #pragma unroll
      for (int p = 0; p < 4; p++) {
        int off = p * 4096 + tid * 16;
        int kr = off >> 8, kc4 = (off & 255) >> 4;
        GLOAD16((const char*)Kp + (size_t)kr * 256 + ((kc4 ^ (kr & 7)) << 4),
                (char*)Ks[0] + off);
        int vr = off >> 7, vc4 = (off & 127) >> 4;
        GLOAD16((const char*)Vp + (size_t)vr * (TDIM * 2) + ((vc4 ^ (vr & 7)) << 4),
                (char*)Vs[0] + off);
      }
    }
    __syncthreads();

    int cur = 0;
    for (int t = 0; t < nt; t++) {
      // ---- issue stage of tile t+1 into the other buffer (hidden by compute)
      if (t + 1 < nt) {
        int kv0n = (t + 1) * 64;
        char* KsN = (char*)Ks[cur ^ 1];
        char* VsN = (char*)Vs[cur ^ 1];
        #pragma unroll
        for (int p = 0; p < 4; p++) {
          int off = p * 4096 + tid * 16;
          int kr = off >> 8, kc4 = (off & 255) >> 4;
          GLOAD16((const char*)Kp + (size_t)(kv0n + kr) * 256 +
                      ((kc4 ^ (kr & 7)) << 4),
                  KsN + off);
          int vr = off >> 7, vc4 = (off & 127) >> 4;
          GLOAD16((const char*)Vp + (size_t)vr * (TDIM * 2) + (size_t)kv0n * 2 +
                      ((vc4 ^ (vr & 7)) << 4),
                  VsN + off);
        }
      }

      const u16* KsC = Ks[cur];
      const u16* VsC = Vs[cur];
      const int kv0 = t * 64;

      // ---- S = Q @ K^T (16 x 64 per wave) ----
      f32x4 sa[4];
      #pragma unroll
      for (int n = 0; n < 4; n++) sa[n] = zero;
      __builtin_amdgcn_s_setprio(1);
      #pragma unroll
      for (int n = 0; n < 4; n++) {
        int krow = n * 16 + c;
        #pragma unroll
        for (int kc = 0; kc < 4; kc++) {
          int kb = (kc * 32 + g * 8) * 2;
          bf16x8 kf = *(const bf16x8*)((const char*)KsC + krow * 256 +
                                       (kb ^ ((krow & 7) << 4)));
          sa[n] = __builtin_amdgcn_mfma_f32_16x16x32_bf16(qf[kc], kf, sa[n], 0, 0, 0);
        }
      }
      __builtin_amdgcn_s_setprio(0);

      // ---- causal mask (only tiles straddling the diagonal) ----
      if (kv0 + 63 > qb) {
        #pragma unroll
        for (int n = 0; n < 4; n++) {
          int col = kv0 + n * 16 + c;
          #pragma unroll
          for (int r = 0; r < 4; r++) {
            int qrow = qb + g * 4 + r;
            if (col > qrow) sa[n][r] = -1e30f;
          }
        }
      }

      // ---- online softmax (rows g*4+r, cols n*16+c) ----
      float pvals[4][4];
      #pragma unroll
      for (int r = 0; r < 4; r++) {
        float vmax = fmaxf(fmaxf(sa[0][r], sa[1][r]), fmaxf(sa[2][r], sa[3][r]));
        #pragma unroll
        for (int d = 1; d < 16; d <<= 1) vmax = fmaxf(vmax, __shfl_xor(vmax, d, 64));
        float mnew = fmaxf(mrun[r], vmax);
        float scale = __expf(mrun[r] - mnew);
        float rs = 0.f;
        #pragma unroll
        for (int n = 0; n < 4; n++) {
          float p = __expf(sa[n][r] - mnew);
          pvals[r][n] = p;
          rs += p;
        }
        #pragma unroll
        for (int d = 1; d < 16; d <<= 1) rs += __shfl_xor(rs, d, 64);
        lrun[r] = lrun[r] * scale + rs;
        mrun[r] = mnew;
        #pragma unroll
        for (int df = 0; df < 8; df++) po[df][r] *= scale;
      }

      // ---- P -> LDS (per-wave, swizzled), then PV ----
      char* Pw = (char*)&Ps[w][0];
      #pragma unroll
      for (int r = 0; r < 4; r++) {
        int ri = g * 4 + r;
        #pragma unroll
        for (int n = 0; n < 4; n++) {
          int colb = (n * 16 + c) * 2;
          *(u16*)(Pw + ri * 128 + (colb ^ ((ri & 7) << 4))) = f2bf(pvals[r][n]);
        }
      }
      bf16x8 pa[2];
      #pragma unroll
      for (int kc2 = 0; kc2 < 2; kc2++) {
        int pb = (kc2 * 32 + g * 8) * 2;
        pa[kc2] = *(const bf16x8*)(Pw + c * 128 + (pb ^ ((c & 7) << 4)));
      }
      __builtin_amdgcn_s_setprio(1);
      #pragma unroll
      for (int df = 0; df < 8; df++) {
        #pragma unroll
        for (int kc2 = 0; kc2 < 2; kc2++) {
          int vrow = df * 16 + c;
          int vb = (kc2 * 32 + g * 8) * 2;
          bf16x8 vf = *(const bf16x8*)((const char*)VsC + vrow * 128 +
                                       (vb ^ ((vrow & 7) << 4)));
          po[df] = __builtin_amdgcn_mfma_f32_16x16x32_bf16(pa[kc2], vf, po[df], 0, 0, 0);
        }
      }
      __builtin_amdgcn_s_setprio(0);

      // one drain per tile: waits this wave's stage loads (issued pre-compute),
      // barrier makes them globally visible before next iteration reads them
      __syncthreads();
      cur ^= 1;
    }

    float inv[4];
    #pragma unroll
    for (int r = 0; r < 4; r++) inv[r] = 1.0f / lrun[r];
    #pragma unroll
    for (int df = 0; df < 8; df++) {
      #pragma unroll
      for (int r = 0; r < 4; r++) {
        int trow = qb + g * 4 + r;
        int col = h * DHEAD + df * 16 + c;
        Yattn[((size_t)b * TDIM + trow) * DMODEL + col] = f2bf(po[df][r] * inv[r]);
      }
    }
    // epilogue touches no LDS; next half's prologue stage is safe after the
    // final in-loop __syncthreads.
  }
}

extern "C" void kernel_launch(void* const* d_in, const int* in_sizes, int n_in,
                              void* d_out, int out_size, void* d_ws, size_t ws_size,
                              hipStream_t stream) {
  const float* x    = (const float*)d_in[0];
  // d_in[1] = mask (exact causal triu; implemented analytically)
  const float* Wqkv = (const float*)d_in[2];
  const float* bqkv = (const float*)d_in[3];
  const float* Wo   = (const float*)d_in[4];
  const float* bo   = (const float*)d_in[5];
  float* out = (float*)d_out;

  char* ws = (char*)d_ws;
  size_t o = 0;
  u16* xb    = (u16*)(ws + o); o += (size_t)NTOK * DMODEL * 2;     // 16.8 MB
  u16* Wqkvt = (u16*)(ws + o); o += (size_t)NQKV * DMODEL * 2;     // 25.2 MB
  u16* Wot   = (u16*)(ws + o); o += (size_t)DMODEL * DMODEL * 2;   // 8.4 MB
  u16* Qb    = (u16*)(ws + o); o += (size_t)BHTOT * TDIM * DHEAD * 2;
  u16* Kb    = (u16*)(ws + o); o += (size_t)BHTOT * TDIM * DHEAD * 2;
  u16* Vtmp  = (u16*)(ws + o); o += (size_t)BHTOT * TDIM * DHEAD * 2;
  float* ct  = (float*)(ws + o); o += (size_t)TDIM * 64 * 4;
  float* st  = (float*)(ws + o); o += (size_t)TDIM * 64 * 4;
  u16* Vt    = xb;    // alias: xb dead after GEMM1
  u16* Yattn = Vtmp;  // alias: Vtmp dead after vtrans

  dim3 tb32x8(32, 8);

  rope_table_kernel<<<(TDIM * 64) / 256, 256, 0, stream>>>(ct, st);
  convert_kernel<<<(NTOK * DMODEL / 4) / 256, 256, 0, stream>>>(x, xb);
  transpose_convert_kernel<<<dim3(NQKV / 32, DMODEL / 32), tb32x8, 0, stream>>>(
      Wqkv, Wqkvt, DMODEL, NQKV);
  transpose_convert_kernel<<<dim3(DMODEL / 32, DMODEL / 32), tb32x8, 0, stream>>>(
      Wo, Wot, DMODEL, DMODEL);

  gemm_bt_kernel<0><<<dim3(NTOK / 128, NQKV / 128), 256, 0, stream>>>(
      xb, Wqkvt, bqkv, Qb, Kb, Vtmp, nullptr, DMODEL);

  rope_kernel<<<(BHTOT * TDIM * 64) / 256, 256, 0, stream>>>(
      Qb, ct, st, 0.08838834764831845f);  // 1/sqrt(128)
  rope_kernel<<<(BHTOT * TDIM * 64) / 256, 256, 0, stream>>>(Kb, ct, st, 1.0f);

  vtrans_kernel<<<dim3(TDIM / 32, DHEAD / 32, BHTOT), tb32x8, 0, stream>>>(Vtmp, Vt);

  // causal-paired q-tiles: grid.x = 16 pairs, each block does {i, 31-i}
  attn_kernel<<<dim3(16, BHTOT), 256, 0, stream>>>(Qb, Kb, Vt, Yattn);

  gemm_bt_kernel<1><<<dim3(NTOK / 128, DMODEL / 128), 256, 0, stream>>>(
      Yattn, Wot, bo, nullptr, nullptr, nullptr, out, DMODEL);
}

// Round 3
// 305.594 us; speedup vs baseline: 1.7104x; 1.2009x over previous
//
#include <hip/hip_runtime.h>
#include <stdint.h>

#define TDIM 2048
#define DMODEL 2048
#define NHEADS 16
#define DHEAD 128
#define NBATCH 2
#define NTOK (NBATCH * TDIM)   // 4096
#define NQKV (3 * DMODEL)      // 6144
#define BHTOT (NBATCH * NHEADS) // 32

typedef unsigned short u16;
typedef __attribute__((ext_vector_type(8))) short bf16x8;
typedef __attribute__((ext_vector_type(4))) float f32x4;
typedef __attribute__((ext_vector_type(4))) int i32x4;

__device__ __forceinline__ u16 f2bf(float f) {
  union { float f; uint32_t u; } v; v.f = f;
  uint32_t u = v.u + 0x7fffu + ((v.u >> 16) & 1u);
  return (u16)(u >> 16);
}
__device__ __forceinline__ float bf2f(u16 h) {
  union { uint32_t u; float f; } v; v.u = ((uint32_t)h) << 16;
  return v.f;
}

#define GLOAD16(g, l)                                                        \
  __builtin_amdgcn_global_load_lds(                                          \
      (const __attribute__((address_space(1))) void*)(g),                    \
      (__attribute__((address_space(3))) void*)(l), 16, 0, 0)

// ---------------- RoPE cos/sin table: ct/st[t][m], m in [0,64) ------------
__global__ void rope_table_kernel(float* __restrict__ ct, float* __restrict__ st) {
  int idx = blockIdx.x * 256 + threadIdx.x;   // TDIM*64 total
  int t = idx >> 6, m = idx & 63;
  float inv = expf(-(float)m * (9.210340371976184f / 64.0f));
  float ang = (float)t * inv;
  ct[idx] = cosf(ang);
  st[idx] = sinf(ang);
}

// ---------------- fp32 -> bf16 elementwise convert (float4) ---------------
__global__ void convert_kernel(const float* __restrict__ in, u16* __restrict__ out) {
  int i = blockIdx.x * 256 + threadIdx.x;
  float4 v = ((const float4*)in)[i];
  ushort4 o;
  o.x = f2bf(v.x); o.y = f2bf(v.y); o.z = f2bf(v.z); o.w = f2bf(v.w);
  ((ushort4*)out)[i] = o;
}

// ------------- fp32 (K,N) row-major -> bf16 (N,K) transposed ---------------
__global__ __launch_bounds__(256) void transpose_convert_kernel(
    const float* __restrict__ in, u16* __restrict__ out, int K, int N) {
  __shared__ u16 tile[32][33];
  int n0 = blockIdx.x * 32, k0 = blockIdx.y * 32;
  int tx = threadIdx.x, ty = threadIdx.y;
  #pragma unroll
  for (int q = 0; q < 4; q++) {
    int k = ty + q * 8;
    tile[k][tx] = f2bf(in[(size_t)(k0 + k) * N + n0 + tx]);
  }
  __syncthreads();
  #pragma unroll
  for (int q = 0; q < 4; q++) {
    int n = ty + q * 8;
    out[(size_t)(n0 + n) * K + k0 + tx] = tile[tx][n];
  }
}

// ---------------- bf16 transpose [BH][T][D] -> [BH][D][T] ------------------
__global__ __launch_bounds__(256) void vtrans_kernel(
    const u16* __restrict__ Vtmp, u16* __restrict__ Vt) {
  __shared__ u16 tile[32][33];
  int bh = blockIdx.z;
  int t0 = blockIdx.x * 32, d0 = blockIdx.y * 32;
  int tx = threadIdx.x, ty = threadIdx.y;
  const u16* src = Vtmp + (size_t)bh * TDIM * DHEAD;
  u16* dst = Vt + (size_t)bh * DHEAD * TDIM;
  #pragma unroll
  for (int q = 0; q < 4; q++) {
    int t = ty + q * 8;
    tile[t][tx] = src[(size_t)(t0 + t) * DHEAD + d0 + tx];
  }
  __syncthreads();
  #pragma unroll
  for (int q = 0; q < 4; q++) {
    int d = ty + q * 8;
    dst[(size_t)(d0 + d) * TDIM + t0 + tx] = tile[tx][d];
  }
}

// ---------------- in-place RoPE on [BH][T][128] bf16 ----------------------
__global__ void rope_kernel(u16* __restrict__ X, const float* __restrict__ ct,
                            const float* __restrict__ st, float scale) {
  int idx = blockIdx.x * 256 + threadIdx.x;   // BH*T*64 pairs
  int i = idx & 63;
  int t = (idx >> 6) & (TDIM - 1);
  size_t base = (size_t)idx * 2;
  float x0 = bf2f(X[base]), x1 = bf2f(X[base + 1]);
  int j0 = (2 * i) & 63, j1 = (2 * i + 1) & 63;
  const float* ctt = ct + (size_t)t * 64;
  const float* stt = st + (size_t)t * 64;
  float c0 = ctt[j0], s0 = stt[j0], c1 = ctt[j1], s1 = stt[j1];
  X[base]     = f2bf((x0 * c0 - x1 * s0) * scale);
  X[base + 1] = f2bf((x1 * c1 + x0 * s1) * scale);
}

// ---------------- deep-pipelined GEMM: A (M,K) @ Bt (N,K), bf16 -----------
// BM=128 BN=256 BK=64, 512 threads (8 waves 2x4), double-buffered 96KB LDS,
// counted-vmcnt prefetch (T4), XOR chunk-swizzle j^=(row&7) both-sides (T2),
// 2 sub-phase K-step (T3-lite), setprio around MFMA (T5).
// MODE 0: + bias -> scatter bf16 into Q/K/V [b][h][t][d]
// MODE 1: + bias -> fp32 row-major out (N=DMODEL)
template <int MODE>
__global__ __launch_bounds__(512, 2) void gemm_bt_kernel(
    const u16* __restrict__ A, const u16* __restrict__ Bt,
    const float* __restrict__ bias,
    u16* __restrict__ q_out, u16* __restrict__ k_out, u16* __restrict__ v_out,
    float* __restrict__ f_out, int K) {
  // per buffer: A 128x64 bf16 = 16384 B, B 256x64 bf16 = 32768 B
  __shared__ __attribute__((aligned(128))) char lds[2][49152];
  const int tid = threadIdx.x;
  const int lane = tid & 63, w = tid >> 6;
  const int wr = w >> 2, wc = w & 3;          // wave grid 2 x 4
  const int g = lane >> 4, c = lane & 15;
  const int m0 = blockIdx.x * 128, n0 = blockIdx.y * 256;
  const size_t rowb = (size_t)K * 2;
  const int NKT = K >> 6;

  // ---- per-thread staging sources (pre-swizzled global chunks, rule 21) ----
  const char* aSrc[2]; int aDst[2];
  const char* bSrc[4]; int bDst[4];
  #pragma unroll
  for (int p = 0; p < 2; p++) {
    int o = p * 8192 + tid * 16;
    int row = o >> 7, j = (o >> 4) & 7;
    aSrc[p] = (const char*)A + (size_t)(m0 + row) * rowb + ((j ^ (row & 7)) << 4);
    aDst[p] = o;
  }
  #pragma unroll
  for (int p = 0; p < 4; p++) {
    int o = p * 8192 + tid * 16;
    int row = o >> 7, j = (o >> 4) & 7;
    bSrc[p] = (const char*)Bt + (size_t)(n0 + row) * rowb + ((j ^ (row & 7)) << 4);
    bDst[p] = 16384 + o;
  }

#define STAGE(bufp, kt)                                                      \
  {                                                                          \
    const size_t kb_ = (size_t)(kt) * 128;                                   \
    _Pragma("unroll") for (int p_ = 0; p_ < 2; p_++)                         \
        GLOAD16(aSrc[p_] + kb_, (bufp) + aDst[p_]);                          \
    _Pragma("unroll") for (int p_ = 0; p_ < 4; p_++)                         \
        GLOAD16(bSrc[p_] + kb_, (bufp) + bDst[p_]);                          \
  }

  // ---- per-wave LDS fragment read offsets (swizzled) ----
  int aRd[4][2], bRd[4][2];
  #pragma unroll
  for (int m = 0; m < 4; m++) {
    #pragma unroll
    for (int ks = 0; ks < 2; ks++) {
      int arow = wr * 64 + m * 16 + c;
      aRd[m][ks] = arow * 128 + (((ks * 4 + g) ^ (c & 7)) << 4);
      int brow = wc * 64 + m * 16 + c;
      bRd[m][ks] = 16384 + brow * 128 + (((ks * 4 + g) ^ (c & 7)) << 4);
    }
  }

  const f32x4 zero = {0.f, 0.f, 0.f, 0.f};
  f32x4 acc[4][4];
  #pragma unroll
  for (int m = 0; m < 4; m++)
    #pragma unroll
    for (int n = 0; n < 4; n++) acc[m][n] = zero;

  // ---- prologue: 2 tiles in flight, wait the first ----
  STAGE(lds[0], 0);
  STAGE(lds[1], 1);
  asm volatile("s_waitcnt vmcnt(6)" ::: "memory");
  __builtin_amdgcn_s_barrier();
  __builtin_amdgcn_sched_barrier(0);

  int cur = 0;
  for (int kt = 0; kt < NKT; kt++) {
    char* bp = cur ? lds[1] : lds[0];
    bf16x8 bfr[4][2], afr[2][2], af2[2][2];
    // SUB1: B frags (all) + A frags m=0..1, then 16 MFMA
    #pragma unroll
    for (int n = 0; n < 4; n++)
      #pragma unroll
      for (int ks = 0; ks < 2; ks++)
        bfr[n][ks] = *(const bf16x8*)(bp + bRd[n][ks]);
    #pragma unroll
    for (int m = 0; m < 2; m++)
      #pragma unroll
      for (int ks = 0; ks < 2; ks++)
        afr[m][ks] = *(const bf16x8*)(bp + aRd[m][ks]);
    __builtin_amdgcn_s_setprio(1);
    #pragma unroll
    for (int ks = 0; ks < 2; ks++)
      #pragma unroll
      for (int m = 0; m < 2; m++)
        #pragma unroll
        for (int n = 0; n < 4; n++)
          acc[m][n] = __builtin_amdgcn_mfma_f32_16x16x32_bf16(
              afr[m][ks], bfr[n][ks], acc[m][n], 0, 0, 0);
    __builtin_amdgcn_s_setprio(0);

    // SUB2: A frags m=2..3, retire all reads, barrier, re-stage, 16 MFMA
    #pragma unroll
    for (int m = 0; m < 2; m++)
      #pragma unroll
      for (int ks = 0; ks < 2; ks++)
        af2[m][ks] = *(const bf16x8*)(bp + aRd[m + 2][ks]);
    asm volatile("s_waitcnt lgkmcnt(0)" ::: "memory");
    __builtin_amdgcn_s_barrier();           // all waves done READING bp
    __builtin_amdgcn_sched_barrier(0);
    if (kt + 2 < NKT) STAGE(bp, kt + 2);    // overwrite freed buffer
    __builtin_amdgcn_s_setprio(1);
    #pragma unroll
    for (int ks = 0; ks < 2; ks++)
      #pragma unroll
      for (int m = 0; m < 2; m++)
        #pragma unroll
        for (int n = 0; n < 4; n++)
          acc[m + 2][n] = __builtin_amdgcn_mfma_f32_16x16x32_bf16(
              af2[m][ks], bfr[n][ks], acc[m + 2][n], 0, 0, 0);
    __builtin_amdgcn_s_setprio(0);

    if (kt < NKT - 1) {
      // next tile's loads (issued one iteration ago) must have landed;
      // keep this iteration's 6 prefetch loads in flight (T4: never 0).
      if (kt + 2 < NKT) {
        asm volatile("s_waitcnt vmcnt(6)" ::: "memory");
      } else {
        asm volatile("s_waitcnt vmcnt(0)" ::: "memory");
      }
      __builtin_amdgcn_s_barrier();
      __builtin_amdgcn_sched_barrier(0);
    }
    cur ^= 1;
  }
#undef STAGE

  // ---- epilogue: D row=(lane>>4)*4+r (A rows), col=lane&15 (B rows) ----
  #pragma unroll
  for (int m = 0; m < 4; m++) {
    #pragma unroll
    for (int n = 0; n < 4; n++) {
      int gcol = n0 + wc * 64 + n * 16 + c;
      float bv = bias[gcol];
      #pragma unroll
      for (int r = 0; r < 4; r++) {
        int grow = m0 + wr * 64 + m * 16 + g * 4 + r;
        float val = acc[m][n][r] + bv;
        if (MODE == 0) {
          int s = gcol >> 11;          // 0:q 1:k 2:v (uniform per block)
          int rem = gcol & 2047;
          int h = rem >> 7, d = rem & 127;
          int b = grow >> 11, t = grow & (TDIM - 1);
          size_t off = (((size_t)(b * NHEADS + h)) * TDIM + t) * DHEAD + d;
          u16 hv = f2bf(val);
          if (s == 0) q_out[off] = hv;
          else if (s == 1) k_out[off] = hv;
          else v_out[off] = hv;
        } else {
          f_out[(size_t)grow * DMODEL + gcol] = val;
        }
      }
    }
  }
}

// ---------------- Flash attention (causal), 4 waves x 16 q-rows -----------
// Double-buffered K/V staging via global_load_lds (linear dest, pre-swizzled
// source); causal-paired q-tiles {i, 31-i} for uniform block work.
// Q,K: [BH][T][128] bf16 (Q pre-scaled); Vt: [BH][128][T]; Yattn: [B][T][HD]
__global__ __launch_bounds__(256) void attn_kernel(
    const u16* __restrict__ Q, const u16* __restrict__ K,
    const u16* __restrict__ Vt, u16* __restrict__ Yattn) {
  __shared__ u16 Ks[2][64 * 128];   // [kv][d], swizzle: chunk ^= row&7
  __shared__ u16 Vs[2][128 * 64];   // [d][kv], swizzle: chunk ^= row&7
  __shared__ u16 Ps[4][16 * 64];    // per-wave P tile, swizzled
  const int tid = threadIdx.x, lane = tid & 63, w = tid >> 6;
  const int g = lane >> 4, c = lane & 15;
  const int bh = blockIdx.y, b = bh >> 4, h = bh & 15;
  const u16* Qp = Q + (size_t)bh * TDIM * DHEAD;
  const u16* Kp = K + (size_t)bh * TDIM * DHEAD;
  const u16* Vp = Vt + (size_t)bh * DHEAD * TDIM;
  const f32x4 zero = {0.f, 0.f, 0.f, 0.f};

  for (int half = 0; half < 2; half++) {
    const int qt = half ? (31 - (int)blockIdx.x) : (int)blockIdx.x;
    const int qb = qt * 64 + w * 16;

    bf16x8 qf[4];
    #pragma unroll
    for (int kc = 0; kc < 4; kc++)
      qf[kc] = *(const bf16x8*)(Qp + (size_t)(qb + c) * DHEAD + kc * 32 + g * 8);

    f32x4 po[8];
    #pragma unroll
    for (int df = 0; df < 8; df++) po[df] = zero;
    float mrun[4], lrun[4];
    #pragma unroll
    for (int r = 0; r < 4; r++) { mrun[r] = -1e30f; lrun[r] = 0.f; }

    const int nt = qt + 1;

    // ---- prologue: stage tile 0 into buf 0 ----
    {
      #pragma unroll
      for (int p = 0; p < 4; p++) {
        int off = p * 4096 + tid * 16;
        int kr = off >> 8, kc4 = (off & 255) >> 4;
        GLOAD16((const char*)Kp + (size_t)kr * 256 + ((kc4 ^ (kr & 7)) << 4),
                (char*)Ks[0] + off);
        int vr = off >> 7, vc4 = (off & 127) >> 4;
        GLOAD16((const char*)Vp + (size_t)vr * (TDIM * 2) + ((vc4 ^ (vr & 7)) << 4),
                (char*)Vs[0] + off);
      }
    }
    __syncthreads();

    int cur = 0;
    for (int t = 0; t < nt; t++) {
      // ---- issue stage of tile t+1 into the other buffer (hidden by compute)
      if (t + 1 < nt) {
        int kv0n = (t + 1) * 64;
        char* KsN = (char*)Ks[cur ^ 1];
        char* VsN = (char*)Vs[cur ^ 1];
        #pragma unroll
        for (int p = 0; p < 4; p++) {
          int off = p * 4096 + tid * 16;
          int kr = off >> 8, kc4 = (off & 255) >> 4;
          GLOAD16((const char*)Kp + (size_t)(kv0n + kr) * 256 +
                      ((kc4 ^ (kr & 7)) << 4),
                  KsN + off);
          int vr = off >> 7, vc4 = (off & 127) >> 4;
          GLOAD16((const char*)Vp + (size_t)vr * (TDIM * 2) + (size_t)kv0n * 2 +
                      ((vc4 ^ (vr & 7)) << 4),
                  VsN + off);
        }
      }

      const u16* KsC = Ks[cur];
      const u16* VsC = Vs[cur];
      const int kv0 = t * 64;

      // ---- S = Q @ K^T (16 x 64 per wave) ----
      f32x4 sa[4];
      #pragma unroll
      for (int n = 0; n < 4; n++) sa[n] = zero;
      __builtin_amdgcn_s_setprio(1);
      #pragma unroll
      for (int n = 0; n < 4; n++) {
        int krow = n * 16 + c;
        #pragma unroll
        for (int kc = 0; kc < 4; kc++) {
          int kb = (kc * 32 + g * 8) * 2;
          bf16x8 kf = *(const bf16x8*)((const char*)KsC + krow * 256 +
                                       (kb ^ ((krow & 7) << 4)));
          sa[n] = __builtin_amdgcn_mfma_f32_16x16x32_bf16(qf[kc], kf, sa[n], 0, 0, 0);
        }
      }
      __builtin_amdgcn_s_setprio(0);

      // ---- causal mask (only tiles straddling the diagonal) ----
      if (kv0 + 63 > qb) {
        #pragma unroll
        for (int n = 0; n < 4; n++) {
          int col = kv0 + n * 16 + c;
          #pragma unroll
          for (int r = 0; r < 4; r++) {
            int qrow = qb + g * 4 + r;
            if (col > qrow) sa[n][r] = -1e30f;
          }
        }
      }

      // ---- online softmax (rows g*4+r, cols n*16+c) ----
      float pvals[4][4];
      #pragma unroll
      for (int r = 0; r < 4; r++) {
        float vmax = fmaxf(fmaxf(sa[0][r], sa[1][r]), fmaxf(sa[2][r], sa[3][r]));
        #pragma unroll
        for (int d = 1; d < 16; d <<= 1) vmax = fmaxf(vmax, __shfl_xor(vmax, d, 64));
        float mnew = fmaxf(mrun[r], vmax);
        float scale = __expf(mrun[r] - mnew);
        float rs = 0.f;
        #pragma unroll
        for (int n = 0; n < 4; n++) {
          float p = __expf(sa[n][r] - mnew);
          pvals[r][n] = p;
          rs += p;
        }
        #pragma unroll
        for (int d = 1; d < 16; d <<= 1) rs += __shfl_xor(rs, d, 64);
        lrun[r] = lrun[r] * scale + rs;
        mrun[r] = mnew;
        #pragma unroll
        for (int df = 0; df < 8; df++) po[df][r] *= scale;
      }

      // ---- P -> LDS (per-wave, swizzled), then PV ----
      char* Pw = (char*)&Ps[w][0];
      #pragma unroll
      for (int r = 0; r < 4; r++) {
        int ri = g * 4 + r;
        #pragma unroll
        for (int n = 0; n < 4; n++) {
          int colb = (n * 16 + c) * 2;
          *(u16*)(Pw + ri * 128 + (colb ^ ((ri & 7) << 4))) = f2bf(pvals[r][n]);
        }
      }
      bf16x8 pa[2];
      #pragma unroll
      for (int kc2 = 0; kc2 < 2; kc2++) {
        int pb = (kc2 * 32 + g * 8) * 2;
        pa[kc2] = *(const bf16x8*)(Pw + c * 128 + (pb ^ ((c & 7) << 4)));
      }
      __builtin_amdgcn_s_setprio(1);
      #pragma unroll
      for (int df = 0; df < 8; df++) {
        #pragma unroll
        for (int kc2 = 0; kc2 < 2; kc2++) {
          int vrow = df * 16 + c;
          int vb = (kc2 * 32 + g * 8) * 2;
          bf16x8 vf = *(const bf16x8*)((const char*)VsC + vrow * 128 +
                                       (vb ^ ((vrow & 7) << 4)));
          po[df] = __builtin_amdgcn_mfma_f32_16x16x32_bf16(pa[kc2], vf, po[df], 0, 0, 0);
        }
      }
      __builtin_amdgcn_s_setprio(0);

      // one drain per tile: waits this wave's stage loads (issued pre-compute),
      // barrier makes them globally visible before next iteration reads them
      __syncthreads();
      cur ^= 1;
    }

    float inv[4];
    #pragma unroll
    for (int r = 0; r < 4; r++) inv[r] = 1.0f / lrun[r];
    #pragma unroll
    for (int df = 0; df < 8; df++) {
      #pragma unroll
      for (int r = 0; r < 4; r++) {
        int trow = qb + g * 4 + r;
        int col = h * DHEAD + df * 16 + c;
        Yattn[((size_t)b * TDIM + trow) * DMODEL + col] = f2bf(po[df][r] * inv[r]);
      }
    }
    // epilogue touches no LDS; next half's prologue stage is safe after the
    // final in-loop __syncthreads.
  }
}

extern "C" void kernel_launch(void* const* d_in, const int* in_sizes, int n_in,
                              void* d_out, int out_size, void* d_ws, size_t ws_size,
                              hipStream_t stream) {
  const float* x    = (const float*)d_in[0];
  // d_in[1] = mask (exact causal triu; implemented analytically)
  const float* Wqkv = (const float*)d_in[2];
  const float* bqkv = (const float*)d_in[3];
  const float* Wo   = (const float*)d_in[4];
  const float* bo   = (const float*)d_in[5];
  float* out = (float*)d_out;

  char* ws = (char*)d_ws;
  size_t o = 0;
  u16* xb    = (u16*)(ws + o); o += (size_t)NTOK * DMODEL * 2;     // 16.8 MB
  u16* Wqkvt = (u16*)(ws + o); o += (size_t)NQKV * DMODEL * 2;     // 25.2 MB
  u16* Wot   = (u16*)(ws + o); o += (size_t)DMODEL * DMODEL * 2;   // 8.4 MB
  u16* Qb    = (u16*)(ws + o); o += (size_t)BHTOT * TDIM * DHEAD * 2;
  u16* Kb    = (u16*)(ws + o); o += (size_t)BHTOT * TDIM * DHEAD * 2;
  u16* Vtmp  = (u16*)(ws + o); o += (size_t)BHTOT * TDIM * DHEAD * 2;
  float* ct  = (float*)(ws + o); o += (size_t)TDIM * 64 * 4;
  float* st  = (float*)(ws + o); o += (size_t)TDIM * 64 * 4;
  u16* Vt    = xb;    // alias: xb dead after GEMM1
  u16* Yattn = Vtmp;  // alias: Vtmp dead after vtrans

  dim3 tb32x8(32, 8);

  rope_table_kernel<<<(TDIM * 64) / 256, 256, 0, stream>>>(ct, st);
  convert_kernel<<<(NTOK * DMODEL / 4) / 256, 256, 0, stream>>>(x, xb);
  transpose_convert_kernel<<<dim3(NQKV / 32, DMODEL / 32), tb32x8, 0, stream>>>(
      Wqkv, Wqkvt, DMODEL, NQKV);
  transpose_convert_kernel<<<dim3(DMODEL / 32, DMODEL / 32), tb32x8, 0, stream>>>(
      Wo, Wot, DMODEL, DMODEL);

  // BM=128, BN=256: grid1 = 32x24 = 768 blocks (3/CU exact)
  gemm_bt_kernel<0><<<dim3(NTOK / 128, NQKV / 256), 512, 0, stream>>>(
      xb, Wqkvt, bqkv, Qb, Kb, Vtmp, nullptr, DMODEL);

  rope_kernel<<<(BHTOT * TDIM * 64) / 256, 256, 0, stream>>>(
      Qb, ct, st, 0.08838834764831845f);  // 1/sqrt(128)
  rope_kernel<<<(BHTOT * TDIM * 64) / 256, 256, 0, stream>>>(Kb, ct, st, 1.0f);

  vtrans_kernel<<<dim3(TDIM / 32, DHEAD / 32, BHTOT), tb32x8, 0, stream>>>(Vtmp, Vt);

  // causal-paired q-tiles: grid.x = 16 pairs, each block does {i, 31-i}
  attn_kernel<<<dim3(16, BHTOT), 256, 0, stream>>>(Qb, Kb, Vt, Yattn);

  // grid2 = 32x8 = 256 blocks (1/CU exact)
  gemm_bt_kernel<1><<<dim3(NTOK / 128, DMODEL / 256), 512, 0, stream>>>(
      Yattn, Wot, bo, nullptr, nullptr, nullptr, out, DMODEL);
}

// Round 4
// 294.147 us; speedup vs baseline: 1.7770x; 1.0389x over previous
//
#include <hip/hip_runtime.h>
#include <stdint.h>

#define TDIM 2048
#define DMODEL 2048
#define NHEADS 16
#define DHEAD 128
#define NBATCH 2
#define NTOK (NBATCH * TDIM)   // 4096
#define NQKV (3 * DMODEL)      // 6144
#define BHTOT (NBATCH * NHEADS) // 32

typedef unsigned short u16;
typedef __attribute__((ext_vector_type(8))) short bf16x8;
typedef __attribute__((ext_vector_type(4))) float f32x4;
typedef __attribute__((ext_vector_type(4))) int i32x4;

__device__ __forceinline__ u16 f2bf(float f) {
  union { float f; uint32_t u; } v; v.f = f;
  uint32_t u = v.u + 0x7fffu + ((v.u >> 16) & 1u);
  return (u16)(u >> 16);
}
__device__ __forceinline__ float bf2f(u16 h) {
  union { uint32_t u; float f; } v; v.u = ((uint32_t)h) << 16;
  return v.f;
}

#define GLOAD16(g, l)                                                        \
  __builtin_amdgcn_global_load_lds(                                          \
      (const __attribute__((address_space(1))) void*)(g),                    \
      (__attribute__((address_space(3))) void*)(l), 16, 0, 0)

// ---------------- RoPE cos/sin table: ct/st[t][m], m in [0,64) ------------
__global__ void rope_table_kernel(float* __restrict__ ct, float* __restrict__ st) {
  int idx = blockIdx.x * 256 + threadIdx.x;   // TDIM*64 total
  int t = idx >> 6, m = idx & 63;
  float inv = expf(-(float)m * (9.210340371976184f / 64.0f));
  float ang = (float)t * inv;
  ct[idx] = cosf(ang);
  st[idx] = sinf(ang);
}

// ---------------- fp32 -> bf16 elementwise convert (float4) ---------------
__global__ void convert_kernel(const float* __restrict__ in, u16* __restrict__ out) {
  int i = blockIdx.x * 256 + threadIdx.x;
  float4 v = ((const float4*)in)[i];
  ushort4 o;
  o.x = f2bf(v.x); o.y = f2bf(v.y); o.z = f2bf(v.z); o.w = f2bf(v.w);
  ((ushort4*)out)[i] = o;
}

// ------------- fp32 (K,N) row-major -> bf16 (N,K) transposed ---------------
__global__ __launch_bounds__(256) void transpose_convert_kernel(
    const float* __restrict__ in, u16* __restrict__ out, int K, int N) {
  __shared__ u16 tile[32][33];
  int n0 = blockIdx.x * 32, k0 = blockIdx.y * 32;
  int tx = threadIdx.x, ty = threadIdx.y;
  #pragma unroll
  for (int q = 0; q < 4; q++) {
    int k = ty + q * 8;
    tile[k][tx] = f2bf(in[(size_t)(k0 + k) * N + n0 + tx]);
  }
  __syncthreads();
  #pragma unroll
  for (int q = 0; q < 4; q++) {
    int n = ty + q * 8;
    out[(size_t)(n0 + n) * K + k0 + tx] = tile[tx][n];
  }
}

// ---------------- bf16 transpose [BH][T][D] -> [BH][D][T] ------------------
__global__ __launch_bounds__(256) void vtrans_kernel(
    const u16* __restrict__ Vtmp, u16* __restrict__ Vt) {
  __shared__ u16 tile[32][33];
  int bh = blockIdx.z;
  int t0 = blockIdx.x * 32, d0 = blockIdx.y * 32;
  int tx = threadIdx.x, ty = threadIdx.y;
  const u16* src = Vtmp + (size_t)bh * TDIM * DHEAD;
  u16* dst = Vt + (size_t)bh * DHEAD * TDIM;
  #pragma unroll
  for (int q = 0; q < 4; q++) {
    int t = ty + q * 8;
    tile[t][tx] = src[(size_t)(t0 + t) * DHEAD + d0 + tx];
  }
  __syncthreads();
  #pragma unroll
  for (int q = 0; q < 4; q++) {
    int d = ty + q * 8;
    dst[(size_t)(d0 + d) * TDIM + t0 + tx] = tile[tx][d];
  }
}

// ---------------- deep-pipelined GEMM: A (M,K) @ Bt (N,K), bf16 -----------
// BM=128 BN=256 BK=64, 512 threads (8 waves 2x4), TRIPLE-buffered 144KB LDS,
// one barrier per K-tile, counted vmcnt (2-tile-old loads), T2 swizzle, T5.
// MODE 0: + bias, fused RoPE on Q/K -> scatter bf16 into Q/K/V [b][h][t][d]
// MODE 1: + bias -> fp32 row-major out (N=DMODEL)
template <int MODE>
__global__ __launch_bounds__(512, 2) void gemm_bt_kernel(
    const u16* __restrict__ A, const u16* __restrict__ Bt,
    const float* __restrict__ bias,
    u16* __restrict__ q_out, u16* __restrict__ k_out, u16* __restrict__ v_out,
    float* __restrict__ f_out,
    const float* __restrict__ ct, const float* __restrict__ st, int K) {
  // per buffer: A 128x64 bf16 = 16384 B, B 256x64 bf16 = 32768 B
  __shared__ __attribute__((aligned(128))) char lds[3][49152];
  const int tid = threadIdx.x;
  const int lane = tid & 63, w = tid >> 6;
  const int wr = w >> 2, wc = w & 3;          // wave grid 2 x 4
  const int g = lane >> 4, c = lane & 15;
  const int m0 = blockIdx.x * 128, n0 = blockIdx.y * 256;
  const size_t rowb = (size_t)K * 2;
  const int NKT = K >> 6;

  // ---- per-thread staging sources (pre-swizzled global chunks, rule 21) ----
  const char* aSrc[2]; int aDst[2];
  const char* bSrc[4]; int bDst[4];
  #pragma unroll
  for (int p = 0; p < 2; p++) {
    int o = p * 8192 + tid * 16;
    int row = o >> 7, j = (o >> 4) & 7;
    aSrc[p] = (const char*)A + (size_t)(m0 + row) * rowb + ((j ^ (row & 7)) << 4);
    aDst[p] = o;
  }
  #pragma unroll
  for (int p = 0; p < 4; p++) {
    int o = p * 8192 + tid * 16;
    int row = o >> 7, j = (o >> 4) & 7;
    bSrc[p] = (const char*)Bt + (size_t)(n0 + row) * rowb + ((j ^ (row & 7)) << 4);
    bDst[p] = 16384 + o;
  }

#define STAGE(bufp, kt)                                                      \
  {                                                                          \
    const size_t kb_ = (size_t)(kt) * 128;                                   \
    _Pragma("unroll") for (int p_ = 0; p_ < 2; p_++)                         \
        GLOAD16(aSrc[p_] + kb_, (bufp) + aDst[p_]);                          \
    _Pragma("unroll") for (int p_ = 0; p_ < 4; p_++)                         \
        GLOAD16(bSrc[p_] + kb_, (bufp) + bDst[p_]);                          \
  }

  // ---- per-wave LDS fragment read offsets (swizzled) ----
  int aRd[4][2], bRd[4][2];
  #pragma unroll
  for (int m = 0; m < 4; m++) {
    #pragma unroll
    for (int ks = 0; ks < 2; ks++) {
      int arow = wr * 64 + m * 16 + c;
      aRd[m][ks] = arow * 128 + (((ks * 4 + g) ^ (c & 7)) << 4);
      int brow = wc * 64 + m * 16 + c;
      bRd[m][ks] = 16384 + brow * 128 + (((ks * 4 + g) ^ (c & 7)) << 4);
    }
  }

  const f32x4 zero = {0.f, 0.f, 0.f, 0.f};
  f32x4 acc[4][4];
  #pragma unroll
  for (int m = 0; m < 4; m++)
    #pragma unroll
    for (int n = 0; n < 4; n++) acc[m][n] = zero;

  // ---- prologue: 2 tiles in flight ----
  STAGE(lds[0], 0);
  STAGE(lds[1], 1);

  // ---- main loop: ONE barrier per K-tile ----
  // tile kt reads buf kt%3; STAGE(kt+2) targets (kt+2)%3 == (kt-1)%3, which
  // is free once all waves pass this tile's entry barrier (passing it means
  // their tile-(kt-1) MFMAs issued => ds_reads retired).
  for (int kt = 0; kt < NKT; kt++) {
    if (kt + 1 < NKT) {
      asm volatile("s_waitcnt vmcnt(6)" ::: "memory");  // kt's 6 loads landed
    } else {
      asm volatile("s_waitcnt vmcnt(0)" ::: "memory");  // last tile: drain
    }
    __builtin_amdgcn_s_barrier();
    __builtin_amdgcn_sched_barrier(0);

    char* bp = lds[kt % 3];
    if (kt + 2 < NKT) STAGE(lds[(kt + 2) % 3], kt + 2);

    bf16x8 afr[4][2], bfr[4][2];
    #pragma unroll
    for (int n = 0; n < 4; n++)
      #pragma unroll
      for (int ks = 0; ks < 2; ks++)
        bfr[n][ks] = *(const bf16x8*)(bp + bRd[n][ks]);
    #pragma unroll
    for (int m = 0; m < 4; m++)
      #pragma unroll
      for (int ks = 0; ks < 2; ks++)
        afr[m][ks] = *(const bf16x8*)(bp + aRd[m][ks]);

    __builtin_amdgcn_s_setprio(1);
    #pragma unroll
    for (int ks = 0; ks < 2; ks++)
      #pragma unroll
      for (int m = 0; m < 4; m++)
        #pragma unroll
        for (int n = 0; n < 4; n++)
          acc[m][n] = __builtin_amdgcn_mfma_f32_16x16x32_bf16(
              afr[m][ks], bfr[n][ks], acc[m][n], 0, 0, 0);
    __builtin_amdgcn_s_setprio(0);
    __builtin_amdgcn_sched_barrier(0);
  }
#undef STAGE

  // ---- epilogue: D row=(lane>>4)*4+r (A rows), col=lane&15 (B rows) ----
  #pragma unroll
  for (int m = 0; m < 4; m++) {
    #pragma unroll
    for (int n = 0; n < 4; n++) {
      int gcol = n0 + wc * 64 + n * 16 + c;
      float bv = bias[gcol];
      float val[4];
      #pragma unroll
      for (int r = 0; r < 4; r++) val[r] = acc[m][n][r] + bv;
      if (MODE == 0) {
        int s = n0 >> 11;                // 0:q 1:k 2:v (uniform per block)
        int rem = gcol & 2047;
        int h = rem >> 7, d = rem & 127;
        int b0 = (m0 + wr * 64 + m * 16) >> 11;
        size_t hb = (((size_t)(b0 * NHEADS + h)) * TDIM) * DHEAD + d;
        if (s == 2) {
          #pragma unroll
          for (int r = 0; r < 4; r++) {
            int t = (m0 + wr * 64 + m * 16 + g * 4 + r) & (TDIM - 1);
            v_out[hb + (size_t)t * DHEAD] = f2bf(val[r]);
          }
        } else {
          // fused RoPE: pairs (d, d^1) live in lanes (c, c^1)
          int mf = gcol & 63;            // freq index = d & 63
          float sgn = (c & 1) ? 1.0f : -1.0f;
          u16* dst = (s == 0) ? q_out : k_out;
          float qs = (s == 0) ? 0.08838834764831845f : 1.0f;
          #pragma unroll
          for (int r = 0; r < 4; r++) {
            float part = __shfl_xor(val[r], 1, 64);
            int t = (m0 + wr * 64 + m * 16 + g * 4 + r) & (TDIM - 1);
            float cs = ct[t * 64 + mf], sn = st[t * 64 + mf];
            float rot = (val[r] * cs + sgn * part * sn) * qs;
            dst[hb + (size_t)t * DHEAD] = f2bf(rot);
          }
        }
      } else {
        #pragma unroll
        for (int r = 0; r < 4; r++) {
          int grow = m0 + wr * 64 + m * 16 + g * 4 + r;
          f_out[(size_t)grow * DMODEL + gcol] = val[r];
        }
      }
    }
  }
}

// ---------------- Flash attention (causal), 4 waves x 16 q-rows -----------
// Double-buffered K/V staging via global_load_lds (linear dest, pre-swizzled
// source); causal-paired q-tiles {i, 31-i} for uniform block work.
// Q,K: [BH][T][128] bf16 (Q pre-scaled); Vt: [BH][128][T]; Yattn: [B][T][HD]
__global__ __launch_bounds__(256) void attn_kernel(
    const u16* __restrict__ Q, const u16* __restrict__ K,
    const u16* __restrict__ Vt, u16* __restrict__ Yattn) {
  __shared__ u16 Ks[2][64 * 128];   // [kv][d], swizzle: chunk ^= row&7
  __shared__ u16 Vs[2][128 * 64];   // [d][kv], swizzle: chunk ^= row&7
  __shared__ u16 Ps[4][16 * 64];    // per-wave P tile, swizzled
  const int tid = threadIdx.x, lane = tid & 63, w = tid >> 6;
  const int g = lane >> 4, c = lane & 15;
  const int bh = blockIdx.y, b = bh >> 4, h = bh & 15;
  const u16* Qp = Q + (size_t)bh * TDIM * DHEAD;
  const u16* Kp = K + (size_t)bh * TDIM * DHEAD;
  const u16* Vp = Vt + (size_t)bh * DHEAD * TDIM;
  const f32x4 zero = {0.f, 0.f, 0.f, 0.f};

  for (int half = 0; half < 2; half++) {
    const int qt = half ? (31 - (int)blockIdx.x) : (int)blockIdx.x;
    const int qb = qt * 64 + w * 16;

    bf16x8 qf[4];
    #pragma unroll
    for (int kc = 0; kc < 4; kc++)
      qf[kc] = *(const bf16x8*)(Qp + (size_t)(qb + c) * DHEAD + kc * 32 + g * 8);

    f32x4 po[8];
    #pragma unroll
    for (int df = 0; df < 8; df++) po[df] = zero;
    float mrun[4], lrun[4];
    #pragma unroll
    for (int r = 0; r < 4; r++) { mrun[r] = -1e30f; lrun[r] = 0.f; }

    const int nt = qt + 1;

    // ---- prologue: stage tile 0 into buf 0 ----
    {
      #pragma unroll
      for (int p = 0; p < 4; p++) {
        int off = p * 4096 + tid * 16;
        int kr = off >> 8, kc4 = (off & 255) >> 4;
        GLOAD16((const char*)Kp + (size_t)kr * 256 + ((kc4 ^ (kr & 7)) << 4),
                (char*)Ks[0] + off);
        int vr = off >> 7, vc4 = (off & 127) >> 4;
        GLOAD16((const char*)Vp + (size_t)vr * (TDIM * 2) + ((vc4 ^ (vr & 7)) << 4),
                (char*)Vs[0] + off);
      }
    }
    __syncthreads();

    int cur = 0;
    for (int t = 0; t < nt; t++) {
      // ---- issue stage of tile t+1 into the other buffer (hidden by compute)
      if (t + 1 < nt) {
        int kv0n = (t + 1) * 64;
        char* KsN = (char*)Ks[cur ^ 1];
        char* VsN = (char*)Vs[cur ^ 1];
        #pragma unroll
        for (int p = 0; p < 4; p++) {
          int off = p * 4096 + tid * 16;
          int kr = off >> 8, kc4 = (off & 255) >> 4;
          GLOAD16((const char*)Kp + (size_t)(kv0n + kr) * 256 +
                      ((kc4 ^ (kr & 7)) << 4),
                  KsN + off);
          int vr = off >> 7, vc4 = (off & 127) >> 4;
          GLOAD16((const char*)Vp + (size_t)vr * (TDIM * 2) + (size_t)kv0n * 2 +
                      ((vc4 ^ (vr & 7)) << 4),
                  VsN + off);
        }
      }

      const u16* KsC = Ks[cur];
      const u16* VsC = Vs[cur];
      const int kv0 = t * 64;

      // ---- S = Q @ K^T (16 x 64 per wave) ----
      f32x4 sa[4];
      #pragma unroll
      for (int n = 0; n < 4; n++) sa[n] = zero;
      __builtin_amdgcn_s_setprio(1);
      #pragma unroll
      for (int n = 0; n < 4; n++) {
        int krow = n * 16 + c;
        #pragma unroll
        for (int kc = 0; kc < 4; kc++) {
          int kb = (kc * 32 + g * 8) * 2;
          bf16x8 kf = *(const bf16x8*)((const char*)KsC + krow * 256 +
                                       (kb ^ ((krow & 7) << 4)));
          sa[n] = __builtin_amdgcn_mfma_f32_16x16x32_bf16(qf[kc], kf, sa[n], 0, 0, 0);
        }
      }
      __builtin_amdgcn_s_setprio(0);

      // ---- causal mask (only tiles straddling the diagonal) ----
      if (kv0 + 63 > qb) {
        #pragma unroll
        for (int n = 0; n < 4; n++) {
          int col = kv0 + n * 16 + c;
          #pragma unroll
          for (int r = 0; r < 4; r++) {
            int qrow = qb + g * 4 + r;
            if (col > qrow) sa[n][r] = -1e30f;
          }
        }
      }

      // ---- online softmax (rows g*4+r, cols n*16+c) ----
      float pvals[4][4];
      #pragma unroll
      for (int r = 0; r < 4; r++) {
        float vmax = fmaxf(fmaxf(sa[0][r], sa[1][r]), fmaxf(sa[2][r], sa[3][r]));
        #pragma unroll
        for (int d = 1; d < 16; d <<= 1) vmax = fmaxf(vmax, __shfl_xor(vmax, d, 64));
        float mnew = fmaxf(mrun[r], vmax);
        float scale = __expf(mrun[r] - mnew);
        float rs = 0.f;
        #pragma unroll
        for (int n = 0; n < 4; n++) {
          float p = __expf(sa[n][r] - mnew);
          pvals[r][n] = p;
          rs += p;
        }
        #pragma unroll
        for (int d = 1; d < 16; d <<= 1) rs += __shfl_xor(rs, d, 64);
        lrun[r] = lrun[r] * scale + rs;
        mrun[r] = mnew;
        #pragma unroll
        for (int df = 0; df < 8; df++) po[df][r] *= scale;
      }

      // ---- P -> LDS (per-wave, swizzled), then PV ----
      char* Pw = (char*)&Ps[w][0];
      #pragma unroll
      for (int r = 0; r < 4; r++) {
        int ri = g * 4 + r;
        #pragma unroll
        for (int n = 0; n < 4; n++) {
          int colb = (n * 16 + c) * 2;
          *(u16*)(Pw + ri * 128 + (colb ^ ((ri & 7) << 4))) = f2bf(pvals[r][n]);
        }
      }
      bf16x8 pa[2];
      #pragma unroll
      for (int kc2 = 0; kc2 < 2; kc2++) {
        int pb = (kc2 * 32 + g * 8) * 2;
        pa[kc2] = *(const bf16x8*)(Pw + c * 128 + (pb ^ ((c & 7) << 4)));
      }
      __builtin_amdgcn_s_setprio(1);
      #pragma unroll
      for (int df = 0; df < 8; df++) {
        #pragma unroll
        for (int kc2 = 0; kc2 < 2; kc2++) {
          int vrow = df * 16 + c;
          int vb = (kc2 * 32 + g * 8) * 2;
          bf16x8 vf = *(const bf16x8*)((const char*)VsC + vrow * 128 +
                                       (vb ^ ((vrow & 7) << 4)));
          po[df] = __builtin_amdgcn_mfma_f32_16x16x32_bf16(pa[kc2], vf, po[df], 0, 0, 0);
        }
      }
      __builtin_amdgcn_s_setprio(0);

      // one drain per tile: waits this wave's stage loads (issued pre-compute),
      // barrier makes them globally visible before next iteration reads them
      __syncthreads();
      cur ^= 1;
    }

    float inv[4];
    #pragma unroll
    for (int r = 0; r < 4; r++) inv[r] = 1.0f / lrun[r];
    #pragma unroll
    for (int df = 0; df < 8; df++) {
      #pragma unroll
      for (int r = 0; r < 4; r++) {
        int trow = qb + g * 4 + r;
        int col = h * DHEAD + df * 16 + c;
        Yattn[((size_t)b * TDIM + trow) * DMODEL + col] = f2bf(po[df][r] * inv[r]);
      }
    }
    // epilogue touches no LDS; next half's prologue stage is safe after the
    // final in-loop __syncthreads.
  }
}

extern "C" void kernel_launch(void* const* d_in, const int* in_sizes, int n_in,
                              void* d_out, int out_size, void* d_ws, size_t ws_size,
                              hipStream_t stream) {
  const float* x    = (const float*)d_in[0];
  // d_in[1] = mask (exact causal triu; implemented analytically)
  const float* Wqkv = (const float*)d_in[2];
  const float* bqkv = (const float*)d_in[3];
  const float* Wo   = (const float*)d_in[4];
  const float* bo   = (const float*)d_in[5];
  float* out = (float*)d_out;

  char* ws = (char*)d_ws;
  size_t o = 0;
  u16* xb    = (u16*)(ws + o); o += (size_t)NTOK * DMODEL * 2;     // 16.8 MB
  u16* Wqkvt = (u16*)(ws + o); o += (size_t)NQKV * DMODEL * 2;     // 25.2 MB
  u16* Wot   = (u16*)(ws + o); o += (size_t)DMODEL * DMODEL * 2;   // 8.4 MB
  u16* Qb    = (u16*)(ws + o); o += (size_t)BHTOT * TDIM * DHEAD * 2;
  u16* Kb    = (u16*)(ws + o); o += (size_t)BHTOT * TDIM * DHEAD * 2;
  u16* Vtmp  = (u16*)(ws + o); o += (size_t)BHTOT * TDIM * DHEAD * 2;
  float* ct  = (float*)(ws + o); o += (size_t)TDIM * 64 * 4;
  float* st  = (float*)(ws + o); o += (size_t)TDIM * 64 * 4;
  u16* Vt    = xb;    // alias: xb dead after GEMM1
  u16* Yattn = Vtmp;  // alias: Vtmp dead after vtrans

  dim3 tb32x8(32, 8);

  rope_table_kernel<<<(TDIM * 64) / 256, 256, 0, stream>>>(ct, st);
  convert_kernel<<<(NTOK * DMODEL / 4) / 256, 256, 0, stream>>>(x, xb);
  transpose_convert_kernel<<<dim3(NQKV / 32, DMODEL / 32), tb32x8, 0, stream>>>(
      Wqkv, Wqkvt, DMODEL, NQKV);
  transpose_convert_kernel<<<dim3(DMODEL / 32, DMODEL / 32), tb32x8, 0, stream>>>(
      Wo, Wot, DMODEL, DMODEL);

  // BM=128, BN=256: grid1 = 32x24 = 768 blocks (3/CU exact); RoPE fused.
  gemm_bt_kernel<0><<<dim3(NTOK / 128, NQKV / 256), 512, 0, stream>>>(
      xb, Wqkvt, bqkv, Qb, Kb, Vtmp, nullptr, ct, st, DMODEL);

  vtrans_kernel<<<dim3(TDIM / 32, DHEAD / 32, BHTOT), tb32x8, 0, stream>>>(Vtmp, Vt);

  // causal-paired q-tiles: grid.x = 16 pairs, each block does {i, 31-i}
  attn_kernel<<<dim3(16, BHTOT), 256, 0, stream>>>(Qb, Kb, Vt, Yattn);

  // grid2 = 32x8 = 256 blocks (1/CU exact)
  gemm_bt_kernel<1><<<dim3(NTOK / 128, DMODEL / 256), 512, 0, stream>>>(
      Yattn, Wot, bo, nullptr, nullptr, nullptr, out, nullptr, nullptr, DMODEL);
}